// Round 9
// baseline (1451.787 us; speedup 1.0000x reference)
//
#include <hip/hip_runtime.h>

#define NN 100000   // nodes
#define NR 8        // relations
#define NE 200000   // edges per relation
#define NL 131072   // labels
#define NSEG (NR*NN)            // 800000 softmax segments
#define NB_SCAN 782             // ceil(800000/1024)
#define NPAD (NB_SCAN*1024)     // 800768 padded segment count

typedef __attribute__((ext_vector_type(8))) short short8;
typedef __attribute__((ext_vector_type(4))) float floatx4;

__device__ __forceinline__ unsigned short f2bf(float f) {
    unsigned u = __float_as_uint(f);
    unsigned r = (u + 0x7fff + ((u >> 16) & 1)) >> 16;   // round-nearest-even
    return (unsigned short)r;
}
__device__ __forceinline__ float bf2f(unsigned short s) {
    return __uint_as_float(((unsigned)s) << 16);
}

// ---------- transpose 128x128 (w[k][j] -> wt[j][k]) ----------
__global__ void transpose128(const float* __restrict__ in, float* __restrict__ out) {
    int idx = blockIdx.x * 256 + threadIdx.x;   // 16384 total
    int j = idx >> 7, k = idx & 127;
    out[idx] = in[k * 128 + j];
}

// ---------- fp32 -> bf16 cast (count = grid*256*4 exactly; used for kw only) ----------
__global__ void cast_bf16(const float* __restrict__ src, unsigned short* __restrict__ dst) {
    size_t idx = ((size_t)blockIdx.x * 256 + threadIdx.x) * 4;
    float4 v = *(const float4*)(src + idx);
    ushort4 o;
    o.x = f2bf(v.x); o.y = f2bf(v.y); o.z = f2bf(v.z); o.w = f2bf(v.w);
    *(ushort4*)(dst + idx) = o;
}

// ---------- CSR build: histogram over dst ----------
__global__ void hist_kernel(const int* __restrict__ ei, int* __restrict__ counts) {
    int idx = blockIdx.x * 256 + threadIdx.x;
    if (idx >= NR * NE) return;
    int r = idx / NE, e = idx - r * NE;
    int dst = ei[(size_t)r * 2 * NE + NE + e];
    atomicAdd(&counts[r * NN + dst], 1);
}

// ---------- scan k1 ----------
__global__ __launch_bounds__(256) void scan_k1(const int* __restrict__ counts,
                                               int* __restrict__ rowptr,
                                               int* __restrict__ bsums) {
    __shared__ int wsum[4];
    int t = threadIdx.x, lane = t & 63, w = t >> 6;
    int base = blockIdx.x * 1024 + t * 4;
    int c0 = counts[base], c1 = counts[base + 1], c2 = counts[base + 2], c3 = counts[base + 3];
    int s = c0 + c1 + c2 + c3;
    int inc = s;
#pragma unroll
    for (int off = 1; off < 64; off <<= 1) { int v = __shfl_up(inc, off); if (lane >= off) inc += v; }
    if (lane == 63) wsum[w] = inc;
    __syncthreads();
    int wbase = 0;
    for (int k = 0; k < w; ++k) wbase += wsum[k];
    int ex = wbase + inc - s;
    rowptr[base]     = ex;
    rowptr[base + 1] = ex + c0;
    rowptr[base + 2] = ex + c0 + c1;
    rowptr[base + 3] = ex + c0 + c1 + c2;
    if (t == 255) bsums[blockIdx.x] = wbase + inc;
}

// ---------- scan k2 ----------
__global__ __launch_bounds__(256) void scan_k2(int* __restrict__ bsums, int nb) {
    __shared__ int wsum[4];
    __shared__ int carry_s;
    int t = threadIdx.x, lane = t & 63, w = t >> 6;
    if (t == 0) carry_s = 0;
    __syncthreads();
    for (int base = 0; base < nb; base += 256) {
        int i = base + t;
        int v = (i < nb) ? bsums[i] : 0;
        int inc = v;
#pragma unroll
        for (int off = 1; off < 64; off <<= 1) { int u = __shfl_up(inc, off); if (lane >= off) inc += u; }
        if (lane == 63) wsum[w] = inc;
        __syncthreads();
        int wbase = carry_s;
        for (int k = 0; k < w; ++k) wbase += wsum[k];
        if (i < nb) bsums[i] = wbase + inc - v;
        __syncthreads();
        if (t == 0) carry_s += wsum[0] + wsum[1] + wsum[2] + wsum[3];
        __syncthreads();
    }
}

// ---------- scan k3 ----------
__global__ void scan_k3(int* __restrict__ rowptr, const int* __restrict__ bsums) {
    int i = blockIdx.x * 256 + threadIdx.x;
    if (i <= NSEG) rowptr[i] += bsums[i >> 10];
}

// ---------- CSR fill: es[pos].x = src (dst-sorted); .y filled by softmax ----------
__global__ void fill_kernel(const int* __restrict__ ei, const int* __restrict__ rowptr,
                            int* __restrict__ cursor, int* __restrict__ es_raw) {
    int idx = blockIdx.x * 256 + threadIdx.x;
    if (idx >= NR * NE) return;
    int r = idx / NE, e = idx - r * NE;
    int src = ei[(size_t)r * 2 * NE + e];
    int dst = ei[(size_t)r * 2 * NE + NE + e];
    int g = r * NN + dst;
    int pos = rowptr[g] + atomicAdd(&cursor[g], 1);
    es_raw[2 * pos] = src;
}

// ---------- proj GEMM (fp32 vector; despilled per round-2 lesson) ----------
__global__ __launch_bounds__(256, 3) void gemm_proj(
    const float* __restrict__ A, const float* __restrict__ B,
    const float* __restrict__ bias, float* __restrict__ out, int nrows)
{
    __shared__ float As[128][36];
    __shared__ float Bs[128][36];
    const int tid = threadIdx.x;
    const int row0 = blockIdx.x * 128;
    const int cg = tid & 15;
    const int nb = (tid >> 4) * 8;

    float acc[8][8];
#pragma unroll
    for (int i = 0; i < 8; ++i)
#pragma unroll
        for (int j = 0; j < 8; ++j) acc[i][j] = 0.f;

    for (int k0 = 0; k0 < 128; k0 += 32) {
#pragma unroll
        for (int i = 0; i < 4; ++i) {
            int fi = tid + i * 256;
            int rw = fi >> 3, kq = fi & 7;
            int n = row0 + rw;
            float4 v = make_float4(0.f, 0.f, 0.f, 0.f);
            if (n < nrows) v = *(const float4*)(A + (size_t)n * 128 + k0 + kq * 4);
            *(float4*)&As[rw][kq * 4] = v;
            float4 w = *(const float4*)(B + rw * 128 + k0 + kq * 4);
            *(float4*)&Bs[rw][kq * 4] = w;
        }
        __syncthreads();
#pragma unroll 2
        for (int kq = 0; kq < 8; ++kq) {
            float4 wv[8];
#pragma unroll
            for (int j = 0; j < 8; ++j) wv[j] = *(const float4*)&Bs[cg + 16 * j][kq * 4];
#pragma unroll
            for (int i = 0; i < 8; ++i) {
                float4 xv = *(const float4*)&As[nb + i][kq * 4];
#pragma unroll
                for (int j = 0; j < 8; ++j)
                    acc[i][j] += xv.x * wv[j].x + xv.y * wv[j].y
                               + xv.z * wv[j].z + xv.w * wv[j].w;
            }
        }
        __syncthreads();
    }
#pragma unroll
    for (int i = 0; i < 8; ++i) {
        int n = row0 + nb + i;
        if (n < nrows) {
#pragma unroll
            for (int j = 0; j < 8; ++j) {
                int d = cg + 16 * j;
                out[(size_t)n * 128 + d] = acc[i][j] + bias[d];
            }
        }
    }
}

// ---------- fused gather(LDS) + MFMA semantic-score GEMM, v3 ----------
// Block 512: each thread owns one (node, dim-octet) -- NO pass loop. Gather
// uses a 4-slot clamped-index unroll (es[min(p0+i,p1-1)], alpha zeroed for
// invalid slots): 4 es loads then 8 h16 loads all independent -> 2 latency
// levels total instead of ~2 per edge serially (round-8 lesson: chain-bound).
__global__ __launch_bounds__(512) void fused_score3(
    const int* __restrict__ rowptr, const int2* __restrict__ es,
    const unsigned short* __restrict__ h16,
    const unsigned short* __restrict__ kw16, const float* __restrict__ kb,
    const float* __restrict__ q, float* __restrict__ score)
{
    __shared__ unsigned short Os[64][136];   // 17.4 KB; 272 B rows
    __shared__ float redbuf[8];
    const int t = threadIdx.x;
    const int r = blockIdx.y;
    const int row0 = blockIdx.x * 64;        // grid.x 1563 -> 100032
    const int l = t & 7, nl = t >> 3;        // 64 nodes x 8 dim-octets

    float acc[16];
#pragma unroll
    for (int i = 0; i < 16; ++i) acc[i] = 0.f;

    int n = row0 + nl;
    if (n < NN) {
        int g = r * NN + n;
        int p0 = rowptr[g], p1 = rowptr[g + 1];
        int2 ep[4];
#pragma unroll
        for (int i = 0; i < 4; ++i) {
            int idx = min(p0 + i, p1 - 1); idx = max(idx, 0);
            ep[i] = es[idx];
            if (p0 + i >= p1) ep[i].y = 0;   // alpha = 0.0f for invalid slots
        }
        short8 hv0[4], hv1[4];
#pragma unroll
        for (int i = 0; i < 4; ++i) {
            const unsigned short* hp = h16 + (size_t)ep[i].x * 128 + l * 16;
            hv0[i] = *(const short8*)hp;
            hv1[i] = *(const short8*)(hp + 8);
        }
#pragma unroll
        for (int i = 0; i < 4; ++i) {
            float al = __int_as_float(ep[i].y);
#pragma unroll
            for (int j = 0; j < 8; ++j) acc[j]     += al * bf2f((unsigned short)hv0[i][j]);
#pragma unroll
            for (int j = 0; j < 8; ++j) acc[8 + j] += al * bf2f((unsigned short)hv1[i][j]);
        }
        for (int e = p0 + 4; e < p1; ++e) {   // rare tail (deg > 4)
            int2 ep2 = es[e];
            float al = __int_as_float(ep2.y);
            const unsigned short* hp = h16 + (size_t)ep2.x * 128 + l * 16;
            short8 h0 = *(const short8*)hp;
            short8 h1 = *(const short8*)(hp + 8);
#pragma unroll
            for (int j = 0; j < 8; ++j) acc[j]     += al * bf2f((unsigned short)h0[j]);
#pragma unroll
            for (int j = 0; j < 8; ++j) acc[8 + j] += al * bf2f((unsigned short)h1[j]);
        }
    }
    unsigned short ov[16];
#pragma unroll
    for (int i = 0; i < 16; ++i) ov[i] = f2bf(fmaxf(acc[i], 0.f));  // relu
    *(short8*)&Os[nl][l * 16]     = *(short8*)&ov[0];
    *(short8*)&Os[nl][l * 16 + 8] = *(short8*)&ov[8];
    __syncthreads();

    // MFMA over 8 waves: wave = (row-tile W = wave>>1, dt-half = wave&1).
    // A[m=lane&15][k=quad*8+j] (m89 layout); C/D: col=lane&15, row=quad*4+reg.
    const int wave = t >> 6, lane = t & 63;
    const int W = wave >> 1, dth = wave & 1;
    const int quad = lane >> 4, l16 = lane & 15;
    short8 a[4];
#pragma unroll
    for (int kc = 0; kc < 4; ++kc)
        a[kc] = *(const short8*)&Os[W * 16 + l16][quad * 8 + kc * 32];

    float s = 0.f;
#pragma unroll
    for (int dti = 0; dti < 4; ++dti) {
        int dt = dth * 4 + dti;
        const unsigned short* brow = kw16 + (size_t)(dt * 16 + l16) * 128 + quad * 8;
        floatx4 accv = {0.f, 0.f, 0.f, 0.f};
#pragma unroll
        for (int kc = 0; kc < 4; ++kc) {
            short8 b = *(const short8*)(brow + kc * 32);
            accv = __builtin_amdgcn_mfma_f32_16x16x32_bf16(a[kc], b, accv, 0, 0, 0);
        }
        int d = dt * 16 + l16;
        float kbv = kb[d], qv = q[d];
#pragma unroll
        for (int reg = 0; reg < 4; ++reg) {
            int node = row0 + W * 16 + quad * 4 + reg;
            if (node < NN) {
                float y = accv[reg] + kbv;
                float e2 = __expf(2.f * y);
                float tn = 1.f - 2.f * __builtin_amdgcn_rcpf(e2 + 1.f);   // tanh
                s += tn * qv;
            }
        }
    }
    for (int off = 32; off > 0; off >>= 1) s += __shfl_down(s, off);
    if (lane == 0) redbuf[wave] = s;
    __syncthreads();
    if (t == 0) {
        float tot = 0.f;
#pragma unroll
        for (int i = 0; i < 8; ++i) tot += redbuf[i];
        atomicAdd(score + r, tot);
    }
}

// ---------- per-node attention logits + fused h16 emit ----------
__global__ __launch_bounds__(256) void att_kernel(
    const float* __restrict__ h, const float* __restrict__ asrc_w,
    const float* __restrict__ adst_w, float* __restrict__ a_src,
    float* __restrict__ a_dst, unsigned short* __restrict__ h16)
{
    __shared__ float hs[16][128];
    int n0 = blockIdx.x * 16;
#pragma unroll
    for (int i = 0; i < 2; ++i) {
        int fi = threadIdx.x + i * 256;
        int n = fi >> 5, kq = fi & 31;
        float4 v = make_float4(0.f, 0.f, 0.f, 0.f);
        if (n0 + n < NN) v = *(const float4*)(h + (size_t)(n0 + n) * 128 + kq * 4);
        *(float4*)&hs[n][kq * 4] = v;
    }
    __syncthreads();
    int n = threadIdx.x >> 4, rr = threadIdx.x & 15;
    int r = rr & 7; int isd = rr >> 3;
    const float* w = (isd ? adst_w : asrc_w) + r * 128;
    float acc = 0.f;
#pragma unroll
    for (int kq = 0; kq < 32; ++kq) {
        float4 hv = *(const float4*)&hs[n][kq * 4];
        float4 wv = ((const float4*)w)[kq];
        acc += hv.x * wv.x + hv.y * wv.y + hv.z * wv.z + hv.w * wv.w;
    }
    if (n0 + n < NN) (isd ? a_dst : a_src)[r * NN + n0 + n] = acc;

    // emit bf16 copy of this node tile (h already staged -- saves a 51 MB pass)
    int dq = rr * 8;
    if (n0 + n < NN) {
        unsigned short ov[8];
#pragma unroll
        for (int k = 0; k < 8; ++k) ov[k] = f2bf(hs[n][dq + k]);
        *(short8*)(h16 + (size_t)(n0 + n) * 128 + dq) = *(short8*)ov;
    }
}

// ---------- CSR segment softmax (PyG semantics, +1e-16); alpha -> es[].y ----------
__global__ void softmax_csr(const int* __restrict__ rowptr, int2* __restrict__ es,
                            const float* __restrict__ a_src, const float* __restrict__ a_dst)
{
    int g = blockIdx.x * 256 + threadIdx.x;
    if (g >= NSEG) return;
    int p0 = rowptr[g], p1 = rowptr[g + 1];
    if (p0 == p1) return;
    int r = g / NN;
    float ad = a_dst[g];
    const float* as = a_src + (size_t)r * NN;
    float m = -1e30f;
    for (int i = p0; i < p1; ++i) {
        float l = as[es[i].x] + ad;
        l = l > 0.f ? l : 0.2f * l;           // leaky_relu 0.2
        es[i].y = __float_as_int(l);
        m = fmaxf(m, l);
    }
    float s = 0.f;
    for (int i = p0; i < p1; ++i) {
        float e = __expf(__int_as_float(es[i].y) - m);
        es[i].y = __float_as_int(e);
        s += e;
    }
    float inv = __builtin_amdgcn_rcpf(s + 1e-16f);   // s >= 1 always
    for (int i = p0; i < p1; ++i)
        es[i].y = __float_as_int(__int_as_float(es[i].y) * inv);
}

// ---------- combine: relation-parallel lanes, fp32 exact, 4-slot unroll ----------
// lane = (r = L>>3, dim-octet = L&7). LDS layout [node][lane][17]: 2-way max.
__global__ __launch_bounds__(256, 3) void combine_csr(
    const int* __restrict__ rowptr, const int2* __restrict__ es,
    const float* __restrict__ h, const float* __restrict__ score,
    float* __restrict__ comb)
{
    __shared__ float attn[NR];
    __shared__ float lds[4][64][17];          // 17.4 KB
    int t = threadIdx.x;
    if (t == 0) {
        float sc[NR]; float m = -1e30f;
        for (int r = 0; r < NR; ++r) { sc[r] = score[r] * (1.0f / NN); m = fmaxf(m, sc[r]); }
        float den = 0.f;
        for (int r = 0; r < NR; ++r) { sc[r] = __expf(sc[r] - m); den += sc[r]; }
        for (int r = 0; r < NR; ++r) attn[r] = sc[r] / den;
    }
    __syncthreads();

    int nl = t >> 6;
    int n = blockIdx.x * 4 + nl;              // grid 25000 -> n < 100000 exactly
    int L = t & 63;
    int r = L >> 3;
    int d0 = (L & 7) * 16;
    float a[16];
#pragma unroll
    for (int i = 0; i < 16; ++i) a[i] = 0.f;
    {
        int g = r * NN + n;
        int p0 = rowptr[g], p1 = rowptr[g + 1];
        int2 ep[4];
#pragma unroll
        for (int i = 0; i < 4; ++i) {
            int idx = min(p0 + i, p1 - 1); idx = max(idx, 0);
            ep[i] = es[idx];
            if (p0 + i >= p1) ep[i].y = 0;    // alpha = 0.0f for invalid slots
        }
        float4 hv[4][4];
#pragma unroll
        for (int i = 0; i < 4; ++i) {
            const float* hp = h + (size_t)ep[i].x * 128 + d0;
            hv[i][0] = *(const float4*)hp;
            hv[i][1] = *(const float4*)(hp + 4);
            hv[i][2] = *(const float4*)(hp + 8);
            hv[i][3] = *(const float4*)(hp + 12);
        }
#pragma unroll
        for (int i = 0; i < 4; ++i) {
            float al = __int_as_float(ep[i].y);
#pragma unroll
            for (int j = 0; j < 4; ++j) {
                a[4*j]   += al * hv[i][j].x; a[4*j+1] += al * hv[i][j].y;
                a[4*j+2] += al * hv[i][j].z; a[4*j+3] += al * hv[i][j].w;
            }
        }
        for (int e = p0 + 4; e < p1; ++e) {   // rare tail (deg > 4)
            int2 ep2 = es[e];
            float al = __int_as_float(ep2.y);
            const float* hp = h + (size_t)ep2.x * 128 + d0;
            float4 v0 = *(const float4*)hp;
            float4 v1 = *(const float4*)(hp + 4);
            float4 v2 = *(const float4*)(hp + 8);
            float4 v3 = *(const float4*)(hp + 12);
            a[0]+=al*v0.x; a[1]+=al*v0.y; a[2]+=al*v0.z;  a[3]+=al*v0.w;
            a[4]+=al*v1.x; a[5]+=al*v1.y; a[6]+=al*v1.z;  a[7]+=al*v1.w;
            a[8]+=al*v2.x; a[9]+=al*v2.y; a[10]+=al*v2.z; a[11]+=al*v2.w;
            a[12]+=al*v3.x;a[13]+=al*v3.y;a[14]+=al*v3.z; a[15]+=al*v3.w;
        }
    }
    float w = attn[r];
    float* dst = &lds[nl][L][0];
#pragma unroll
    for (int i = 0; i < 16; ++i) dst[i] = w * fmaxf(a[i], 0.f);   // relu per (n,r)
    __syncthreads();

    // phase 2: sum over relations; dim d=2L lives in phase-1 lane 8*rr + (L>>3),
    // elements 2*(L&7), 2*(L&7)+1
    int o = L >> 3, j = L & 7;
    float s0 = 0.f, s1 = 0.f;
#pragma unroll
    for (int rr = 0; rr < NR; ++rr) {
        s0 += lds[nl][rr * 8 + o][2 * j];
        s1 += lds[nl][rr * 8 + o][2 * j + 1];
    }
    *(float2*)(comb + (size_t)n * 128 + 2 * L) = make_float2(s0, s1);
}

// ---------- link head ----------
__global__ __launch_bounds__(256) void head_kernel(
    const float* __restrict__ hfin, const int* __restrict__ eli,
    const float* __restrict__ pw, const float* __restrict__ pb,
    float* __restrict__ out)
{
    int t = threadIdx.x;
    int l = blockIdx.x * 4 + (t >> 6);        // grid 32768 -> l < 131072 exactly
    int d0 = (t & 63) * 2;
    int a = eli[l], b = eli[NL + l];
    float2 ha = *(const float2*)(hfin + (size_t)a * 128 + d0);
    float2 hb = *(const float2*)(hfin + (size_t)b * 128 + d0);
    float w0 = pw[d0 * 2] + pw[d0 * 2 + 1];
    float w1 = pw[d0 * 2 + 2] + pw[d0 * 2 + 3];
    float v = ha.x * hb.x * w0 + ha.y * hb.y * w1;
    for (int off = 32; off > 0; off >>= 1) v += __shfl_down(v, off);
    if ((t & 63) == 0) out[l] = v + pb[0] + pb[1];
}

extern "C" void kernel_launch(void* const* d_in, const int* in_sizes, int n_in,
                              void* d_out, int out_size, void* d_ws, size_t ws_size,
                              hipStream_t stream)
{
    const float* x     = (const float*)d_in[0];
    const int*   ei    = (const int*)d_in[1];
    const int*   eli   = (const int*)d_in[2];
    const float* w1    = (const float*)d_in[3];
    const float* b1    = (const float*)d_in[4];
    const float* asrc1 = (const float*)d_in[5];
    const float* adst1 = (const float*)d_in[6];
    const float* q1    = (const float*)d_in[7];
    const float* kw1   = (const float*)d_in[8];
    const float* kb1   = (const float*)d_in[9];
    const float* w2    = (const float*)d_in[10];
    const float* b2    = (const float*)d_in[11];
    const float* asrc2 = (const float*)d_in[12];
    const float* adst2 = (const float*)d_in[13];
    const float* q2    = (const float*)d_in[14];
    const float* kw2   = (const float*)d_in[15];
    const float* kb2   = (const float*)d_in[16];
    const float* pw    = (const float*)d_in[17];
    const float* pb    = (const float*)d_in[18];
    float* out = (float*)d_out;

    // ---- workspace layout (float offsets); total ~128.2 MB ----
    float* ws      = (float*)d_ws;
    float* hA      = ws;                         // 12,800,000
    float* hB      = ws + 12800000ull;           // 12,800,000
    float* a_src   = ws + 25600000ull;           // 800,000
    float* a_dst   = ws + 26400000ull;           // 800,000
    int2*  es      = (int2*)(ws + 27200000ull);  // 1,600,000 x int2 (src, alpha)
    int*   rowptr  = (int*)(ws + 30400000ull);   // 800,768 (padded)
    int*   counts  = (int*)(ws + 31200768ull);   // 800,768 (padded; reused as cursor)
    int*   bsums   = (int*)(ws + 32001536ull);   // 1,024
    float* score   = ws + 32002560ull;           // 64
    float* wt      = ws + 32002624ull;           // 16,384
    unsigned short* kw16 = (unsigned short*)(ws + 32019008ull);  // 16,384 ushorts
    // h16 (12.8 MB) aliases hB: hB's previous content (layer input) is dead
    // once gemm_proj consumed it; combine_csr overwrites hB only after the
    // score path has finished reading h16 (stream-ordered).
    unsigned short* h16 = (unsigned short*)hB;

    // ---- CSR build (edge_index is layer-invariant: build once) ----
    hipMemsetAsync(counts, 0, NPAD * sizeof(int), stream);
    hist_kernel<<<6250, 256, 0, stream>>>(ei, counts);
    scan_k1<<<NB_SCAN, 256, 0, stream>>>(counts, rowptr, bsums);
    scan_k2<<<1, 256, 0, stream>>>(bsums, NB_SCAN);
    scan_k3<<<3126, 256, 0, stream>>>(rowptr, bsums);
    hipMemsetAsync(counts, 0, NPAD * sizeof(int), stream);
    fill_kernel<<<6250, 256, 0, stream>>>(ei, rowptr, counts, (int*)es);

    for (int layer = 0; layer < 2; ++layer) {
        const float* Ain  = layer ? hB : x;
        const float* W    = layer ? w2 : w1;
        const float* bb   = layer ? b2 : b1;
        const float* as_w = layer ? asrc2 : asrc1;
        const float* ad_w = layer ? adst2 : adst1;
        const float* qq   = layer ? q2 : q1;
        const float* kw   = layer ? kw2 : kw1;
        const float* kb   = layer ? kb2 : kb1;

        transpose128<<<64, 256, 0, stream>>>(W, wt);
        gemm_proj<<<782, 256, 0, stream>>>(Ain, wt, bb, hA, NN);
        cast_bf16<<<16, 256, 0, stream>>>(kw, kw16);
        att_kernel<<<6250, 256, 0, stream>>>(hA, as_w, ad_w, a_src, a_dst, h16);
        softmax_csr<<<3125, 256, 0, stream>>>(rowptr, es, a_src, a_dst);
        hipMemsetAsync(score, 0, 64 * sizeof(float), stream);
        fused_score3<<<dim3(1563, NR), 512, 0, stream>>>(rowptr, es, h16,
                                                         kw16, kb, qq, score);
        combine_csr<<<25000, 256, 0, stream>>>(rowptr, es, hA, score, hB);
        // hB now holds this layer's output embeddings
    }
    head_kernel<<<32768, 256, 0, stream>>>(hB, eli, pw, pb, out);
}

// Round 10
// 1430.249 us; speedup vs baseline: 1.0151x; 1.0151x over previous
//
#include <hip/hip_runtime.h>

#define NN 100000   // nodes
#define NR 8        // relations
#define NE 200000   // edges per relation
#define NL 131072   // labels
#define NSEG (NR*NN)            // 800000 softmax segments
#define NB_SCAN 782             // ceil(800000/1024)
#define NPAD (NB_SCAN*1024)     // 800768 padded segment count

typedef __attribute__((ext_vector_type(8))) short short8;
typedef __attribute__((ext_vector_type(4))) float floatx4;

__device__ __forceinline__ unsigned short f2bf(float f) {
    unsigned u = __float_as_uint(f);
    unsigned r = (u + 0x7fff + ((u >> 16) & 1)) >> 16;   // round-nearest-even
    return (unsigned short)r;
}
__device__ __forceinline__ float bf2f(unsigned short s) {
    return __uint_as_float(((unsigned)s) << 16);
}

// ---- custom 8-bit float (e4m3, bias 11, no subnormals, flush<2^-10) ----
// score-path only. decode: 5 VALU branchless; encode: RNE via carry trick.
__device__ __forceinline__ unsigned enc8(float x) {
    unsigned u = __float_as_uint(x);
    unsigned s = (u >> 24) & 0x80;
    unsigned a = u & 0x7fffffff;
    unsigned r = a + 0x7FFFF + ((a >> 20) & 1);
    int em = (int)(r >> 20) - 928;          // (127-11)<<3
    em = em < 8 ? 8 : em;                   // flush tiny to +-2^-10
    em = em > 127 ? 127 : em;
    return s | (unsigned)em;
}
__device__ __forceinline__ float dec8(unsigned b) {
    unsigned t = b & 0x7f;
    unsigned mag = (t << 20) + 0x3A000000u; // 116<<23
    unsigned sg = (b & 0x80) << 24;
    return __uint_as_float(mag | sg);
}

// ---------- transpose 128x128 (w[k][j] -> wt[j][k]) ----------
__global__ void transpose128(const float* __restrict__ in, float* __restrict__ out) {
    int idx = blockIdx.x * 256 + threadIdx.x;   // 16384 total
    int j = idx >> 7, k = idx & 127;
    out[idx] = in[k * 128 + j];
}

// ---------- fp32 -> bf16 cast (count = grid*256*4 exactly; used for kw only) ----------
__global__ void cast_bf16(const float* __restrict__ src, unsigned short* __restrict__ dst) {
    size_t idx = ((size_t)blockIdx.x * 256 + threadIdx.x) * 4;
    float4 v = *(const float4*)(src + idx);
    ushort4 o;
    o.x = f2bf(v.x); o.y = f2bf(v.y); o.z = f2bf(v.z); o.w = f2bf(v.w);
    *(ushort4*)(dst + idx) = o;
}

// ---------- CSR build: histogram over dst ----------
__global__ void hist_kernel(const int* __restrict__ ei, int* __restrict__ counts) {
    int idx = blockIdx.x * 256 + threadIdx.x;
    if (idx >= NR * NE) return;
    int r = idx / NE, e = idx - r * NE;
    int dst = ei[(size_t)r * 2 * NE + NE + e];
    atomicAdd(&counts[r * NN + dst], 1);
}

// ---------- scan k1 ----------
__global__ __launch_bounds__(256) void scan_k1(const int* __restrict__ counts,
                                               int* __restrict__ rowptr,
                                               int* __restrict__ bsums) {
    __shared__ int wsum[4];
    int t = threadIdx.x, lane = t & 63, w = t >> 6;
    int base = blockIdx.x * 1024 + t * 4;
    int c0 = counts[base], c1 = counts[base + 1], c2 = counts[base + 2], c3 = counts[base + 3];
    int s = c0 + c1 + c2 + c3;
    int inc = s;
#pragma unroll
    for (int off = 1; off < 64; off <<= 1) { int v = __shfl_up(inc, off); if (lane >= off) inc += v; }
    if (lane == 63) wsum[w] = inc;
    __syncthreads();
    int wbase = 0;
    for (int k = 0; k < w; ++k) wbase += wsum[k];
    int ex = wbase + inc - s;
    rowptr[base]     = ex;
    rowptr[base + 1] = ex + c0;
    rowptr[base + 2] = ex + c0 + c1;
    rowptr[base + 3] = ex + c0 + c1 + c2;
    if (t == 255) bsums[blockIdx.x] = wbase + inc;
}

// ---------- scan k2 ----------
__global__ __launch_bounds__(256) void scan_k2(int* __restrict__ bsums, int nb) {
    __shared__ int wsum[4];
    __shared__ int carry_s;
    int t = threadIdx.x, lane = t & 63, w = t >> 6;
    if (t == 0) carry_s = 0;
    __syncthreads();
    for (int base = 0; base < nb; base += 256) {
        int i = base + t;
        int v = (i < nb) ? bsums[i] : 0;
        int inc = v;
#pragma unroll
        for (int off = 1; off < 64; off <<= 1) { int u = __shfl_up(inc, off); if (lane >= off) inc += u; }
        if (lane == 63) wsum[w] = inc;
        __syncthreads();
        int wbase = carry_s;
        for (int k = 0; k < w; ++k) wbase += wsum[k];
        if (i < nb) bsums[i] = wbase + inc - v;
        __syncthreads();
        if (t == 0) carry_s += wsum[0] + wsum[1] + wsum[2] + wsum[3];
        __syncthreads();
    }
}

// ---------- scan k3 ----------
__global__ void scan_k3(int* __restrict__ rowptr, const int* __restrict__ bsums) {
    int i = blockIdx.x * 256 + threadIdx.x;
    if (i <= NSEG) rowptr[i] += bsums[i >> 10];
}

// ---------- CSR fill: es[pos].x = src (dst-sorted); .y filled by softmax ----------
__global__ void fill_kernel(const int* __restrict__ ei, const int* __restrict__ rowptr,
                            int* __restrict__ cursor, int* __restrict__ es_raw) {
    int idx = blockIdx.x * 256 + threadIdx.x;
    if (idx >= NR * NE) return;
    int r = idx / NE, e = idx - r * NE;
    int src = ei[(size_t)r * 2 * NE + e];
    int dst = ei[(size_t)r * 2 * NE + NE + e];
    int g = r * NN + dst;
    int pos = rowptr[g] + atomicAdd(&cursor[g], 1);
    es_raw[2 * pos] = src;
}

// ---------- proj GEMM (fp32 vector; despilled per round-2 lesson) ----------
__global__ __launch_bounds__(256, 3) void gemm_proj(
    const float* __restrict__ A, const float* __restrict__ B,
    const float* __restrict__ bias, float* __restrict__ out, int nrows)
{
    __shared__ float As[128][36];
    __shared__ float Bs[128][36];
    const int tid = threadIdx.x;
    const int row0 = blockIdx.x * 128;
    const int cg = tid & 15;
    const int nb = (tid >> 4) * 8;

    float acc[8][8];
#pragma unroll
    for (int i = 0; i < 8; ++i)
#pragma unroll
        for (int j = 0; j < 8; ++j) acc[i][j] = 0.f;

    for (int k0 = 0; k0 < 128; k0 += 32) {
#pragma unroll
        for (int i = 0; i < 4; ++i) {
            int fi = tid + i * 256;
            int rw = fi >> 3, kq = fi & 7;
            int n = row0 + rw;
            float4 v = make_float4(0.f, 0.f, 0.f, 0.f);
            if (n < nrows) v = *(const float4*)(A + (size_t)n * 128 + k0 + kq * 4);
            *(float4*)&As[rw][kq * 4] = v;
            float4 w = *(const float4*)(B + rw * 128 + k0 + kq * 4);
            *(float4*)&Bs[rw][kq * 4] = w;
        }
        __syncthreads();
#pragma unroll 2
        for (int kq = 0; kq < 8; ++kq) {
            float4 wv[8];
#pragma unroll
            for (int j = 0; j < 8; ++j) wv[j] = *(const float4*)&Bs[cg + 16 * j][kq * 4];
#pragma unroll
            for (int i = 0; i < 8; ++i) {
                float4 xv = *(const float4*)&As[nb + i][kq * 4];
#pragma unroll
                for (int j = 0; j < 8; ++j)
                    acc[i][j] += xv.x * wv[j].x + xv.y * wv[j].y
                               + xv.z * wv[j].z + xv.w * wv[j].w;
            }
        }
        __syncthreads();
    }
#pragma unroll
    for (int i = 0; i < 8; ++i) {
        int n = row0 + nb + i;
        if (n < nrows) {
#pragma unroll
            for (int j = 0; j < 8; ++j) {
                int d = cg + 16 * j;
                out[(size_t)n * 128 + d] = acc[i][j] + bias[d];
            }
        }
    }
}

// ---------- fused gather(LDS) + MFMA semantic-score GEMM, fp8 rows ----------
// h8 rows are 128 B (half of bf16): halves the random row-gather volume that
// rounds 7-9 showed is the structural floor, and 6.4 MB sits far better in the
// 4 MB per-XCD L2. One dwordx4 per edge per lane; branchless 5-op decode.
__global__ __launch_bounds__(512) void fused_score3(
    const int* __restrict__ rowptr, const int2* __restrict__ es,
    const unsigned char* __restrict__ h8,
    const unsigned short* __restrict__ kw16, const float* __restrict__ kb,
    const float* __restrict__ q, float* __restrict__ score)
{
    __shared__ unsigned short Os[64][136];   // bf16 o-tile, 17.4 KB
    __shared__ float redbuf[8];
    const int t = threadIdx.x;
    const int r = blockIdx.y;
    const int row0 = blockIdx.x * 64;        // grid.x 1563 -> 100032
    const int l = t & 7, nl = t >> 3;        // 64 nodes x 8 dim-octets(16 dims)

    float acc[16];
#pragma unroll
    for (int i = 0; i < 16; ++i) acc[i] = 0.f;

    int n = row0 + nl;
    if (n < NN) {
        int g = r * NN + n;
        int p0 = rowptr[g], p1 = rowptr[g + 1];
        int2 ep[4];
#pragma unroll
        for (int i = 0; i < 4; ++i) {
            int idx = min(p0 + i, p1 - 1); idx = max(idx, 0);
            ep[i] = es[idx];
            if (p0 + i >= p1) ep[i].y = 0;   // alpha = 0.0f for invalid slots
        }
        uint4 hv[4];
#pragma unroll
        for (int i = 0; i < 4; ++i)
            hv[i] = *(const uint4*)(h8 + (size_t)ep[i].x * 128 + l * 16);
#pragma unroll
        for (int i = 0; i < 4; ++i) {
            float al = __int_as_float(ep[i].y);
            const unsigned* up = (const unsigned*)&hv[i];
#pragma unroll
            for (int w = 0; w < 4; ++w) {
                unsigned u = up[w];
                acc[w * 4 + 0] += al * dec8(u & 0xff);
                acc[w * 4 + 1] += al * dec8((u >> 8) & 0xff);
                acc[w * 4 + 2] += al * dec8((u >> 16) & 0xff);
                acc[w * 4 + 3] += al * dec8(u >> 24);
            }
        }
        for (int e = p0 + 4; e < p1; ++e) {   // rare tail (deg > 4)
            int2 ep2 = es[e];
            float al = __int_as_float(ep2.y);
            uint4 hq = *(const uint4*)(h8 + (size_t)ep2.x * 128 + l * 16);
            const unsigned* up = (const unsigned*)&hq;
#pragma unroll
            for (int w = 0; w < 4; ++w) {
                unsigned u = up[w];
                acc[w * 4 + 0] += al * dec8(u & 0xff);
                acc[w * 4 + 1] += al * dec8((u >> 8) & 0xff);
                acc[w * 4 + 2] += al * dec8((u >> 16) & 0xff);
                acc[w * 4 + 3] += al * dec8(u >> 24);
            }
        }
    }
    unsigned short ov[16];
#pragma unroll
    for (int i = 0; i < 16; ++i) ov[i] = f2bf(fmaxf(acc[i], 0.f));  // relu
    *(short8*)&Os[nl][l * 16]     = *(short8*)&ov[0];
    *(short8*)&Os[nl][l * 16 + 8] = *(short8*)&ov[8];
    __syncthreads();

    // MFMA over 8 waves: wave = (row-tile W = wave>>1, dt-half = wave&1).
    // A[m=lane&15][k=quad*8+j] (m89 layout); C/D: col=lane&15, row=quad*4+reg.
    const int wave = t >> 6, lane = t & 63;
    const int W = wave >> 1, dth = wave & 1;
    const int quad = lane >> 4, l16 = lane & 15;
    short8 a[4];
#pragma unroll
    for (int kc = 0; kc < 4; ++kc)
        a[kc] = *(const short8*)&Os[W * 16 + l16][quad * 8 + kc * 32];

    float s = 0.f;
#pragma unroll
    for (int dti = 0; dti < 4; ++dti) {
        int dt = dth * 4 + dti;
        const unsigned short* brow = kw16 + (size_t)(dt * 16 + l16) * 128 + quad * 8;
        floatx4 accv = {0.f, 0.f, 0.f, 0.f};
#pragma unroll
        for (int kc = 0; kc < 4; ++kc) {
            short8 b = *(const short8*)(brow + kc * 32);
            accv = __builtin_amdgcn_mfma_f32_16x16x32_bf16(a[kc], b, accv, 0, 0, 0);
        }
        int d = dt * 16 + l16;
        float kbv = kb[d], qv = q[d];
#pragma unroll
        for (int reg = 0; reg < 4; ++reg) {
            int node = row0 + W * 16 + quad * 4 + reg;
            if (node < NN) {
                float y = accv[reg] + kbv;
                float e2 = __expf(2.f * y);
                float tn = 1.f - 2.f * __builtin_amdgcn_rcpf(e2 + 1.f);   // tanh
                s += tn * qv;
            }
        }
    }
    for (int off = 32; off > 0; off >>= 1) s += __shfl_down(s, off);
    if (lane == 0) redbuf[wave] = s;
    __syncthreads();
    if (t == 0) {
        float tot = 0.f;
#pragma unroll
        for (int i = 0; i < 8; ++i) tot += redbuf[i];
        atomicAdd(score + r, tot);
    }
}

// ---------- per-node attention logits + fused h8 emit ----------
__global__ __launch_bounds__(256) void att_kernel(
    const float* __restrict__ h, const float* __restrict__ asrc_w,
    const float* __restrict__ adst_w, float* __restrict__ a_src,
    float* __restrict__ a_dst, unsigned char* __restrict__ h8)
{
    __shared__ float hs[16][128];
    int n0 = blockIdx.x * 16;
#pragma unroll
    for (int i = 0; i < 2; ++i) {
        int fi = threadIdx.x + i * 256;
        int n = fi >> 5, kq = fi & 31;
        float4 v = make_float4(0.f, 0.f, 0.f, 0.f);
        if (n0 + n < NN) v = *(const float4*)(h + (size_t)(n0 + n) * 128 + kq * 4);
        *(float4*)&hs[n][kq * 4] = v;
    }
    __syncthreads();
    int n = threadIdx.x >> 4, rr = threadIdx.x & 15;
    int r = rr & 7; int isd = rr >> 3;
    const float* w = (isd ? adst_w : asrc_w) + r * 128;
    float acc = 0.f;
#pragma unroll
    for (int kq = 0; kq < 32; ++kq) {
        float4 hv = *(const float4*)&hs[n][kq * 4];
        float4 wv = ((const float4*)w)[kq];
        acc += hv.x * wv.x + hv.y * wv.y + hv.z * wv.z + hv.w * wv.w;
    }
    if (n0 + n < NN) (isd ? a_dst : a_src)[r * NN + n0 + n] = acc;

    // emit fp8 copy of this node tile for the score-path gather
    int dq = rr * 8;
    if (n0 + n < NN) {
        unsigned lo = 0, hi = 0;
#pragma unroll
        for (int k = 0; k < 4; ++k) lo |= enc8(hs[n][dq + k]) << (8 * k);
#pragma unroll
        for (int k = 0; k < 4; ++k) hi |= enc8(hs[n][dq + 4 + k]) << (8 * k);
        *(uint2*)(h8 + (size_t)(n0 + n) * 128 + dq) = make_uint2(lo, hi);
    }
}

// ---------- CSR segment softmax (PyG semantics, +1e-16); alpha -> es[].y ----------
__global__ void softmax_csr(const int* __restrict__ rowptr, int2* __restrict__ es,
                            const float* __restrict__ a_src, const float* __restrict__ a_dst,
                            float* __restrict__ score)
{
    int g = blockIdx.x * 256 + threadIdx.x;
    if (g < NR) score[g] = 0.f;               // fold score-zeroing (saves memset launch)
    if (g >= NSEG) return;
    int p0 = rowptr[g], p1 = rowptr[g + 1];
    if (p0 == p1) return;
    int r = g / NN;
    float ad = a_dst[g];
    const float* as = a_src + (size_t)r * NN;
    float m = -1e30f;
    for (int i = p0; i < p1; ++i) {
        float l = as[es[i].x] + ad;
        l = l > 0.f ? l : 0.2f * l;           // leaky_relu 0.2
        es[i].y = __float_as_int(l);
        m = fmaxf(m, l);
    }
    float s = 0.f;
    for (int i = p0; i < p1; ++i) {
        float e = __expf(__int_as_float(es[i].y) - m);
        es[i].y = __float_as_int(e);
        s += e;
    }
    float inv = __builtin_amdgcn_rcpf(s + 1e-16f);   // s >= 1 always
    for (int i = p0; i < p1; ++i)
        es[i].y = __float_as_int(__int_as_float(es[i].y) * inv);
}

// ---------- combine: relation-parallel lanes, fp32 exact, 4-slot unroll ----------
// lane = (r = L>>3, dim-octet = L&7). LDS layout [node][lane][17]: 2-way max.
__global__ __launch_bounds__(256, 3) void combine_csr(
    const int* __restrict__ rowptr, const int2* __restrict__ es,
    const float* __restrict__ h, const float* __restrict__ score,
    float* __restrict__ comb)
{
    __shared__ float attn[NR];
    __shared__ float lds[4][64][17];          // 17.4 KB
    int t = threadIdx.x;
    if (t == 0) {
        float sc[NR]; float m = -1e30f;
        for (int r = 0; r < NR; ++r) { sc[r] = score[r] * (1.0f / NN); m = fmaxf(m, sc[r]); }
        float den = 0.f;
        for (int r = 0; r < NR; ++r) { sc[r] = __expf(sc[r] - m); den += sc[r]; }
        for (int r = 0; r < NR; ++r) attn[r] = sc[r] / den;
    }
    __syncthreads();

    int nl = t >> 6;
    int n = blockIdx.x * 4 + nl;              // grid 25000 -> n < 100000 exactly
    int L = t & 63;
    int r = L >> 3;
    int d0 = (L & 7) * 16;
    float a[16];
#pragma unroll
    for (int i = 0; i < 16; ++i) a[i] = 0.f;
    {
        int g = r * NN + n;
        int p0 = rowptr[g], p1 = rowptr[g + 1];
        int2 ep[4];
#pragma unroll
        for (int i = 0; i < 4; ++i) {
            int idx = min(p0 + i, p1 - 1); idx = max(idx, 0);
            ep[i] = es[idx];
            if (p0 + i >= p1) ep[i].y = 0;    // alpha = 0.0f for invalid slots
        }
        float4 hv[4][4];
#pragma unroll
        for (int i = 0; i < 4; ++i) {
            const float* hp = h + (size_t)ep[i].x * 128 + d0;
            hv[i][0] = *(const float4*)hp;
            hv[i][1] = *(const float4*)(hp + 4);
            hv[i][2] = *(const float4*)(hp + 8);
            hv[i][3] = *(const float4*)(hp + 12);
        }
#pragma unroll
        for (int i = 0; i < 4; ++i) {
            float al = __int_as_float(ep[i].y);
#pragma unroll
            for (int j = 0; j < 4; ++j) {
                a[4*j]   += al * hv[i][j].x; a[4*j+1] += al * hv[i][j].y;
                a[4*j+2] += al * hv[i][j].z; a[4*j+3] += al * hv[i][j].w;
            }
        }
        for (int e = p0 + 4; e < p1; ++e) {   // rare tail (deg > 4)
            int2 ep2 = es[e];
            float al = __int_as_float(ep2.y);
            const float* hp = h + (size_t)ep2.x * 128 + d0;
            float4 v0 = *(const float4*)hp;
            float4 v1 = *(const float4*)(hp + 4);
            float4 v2 = *(const float4*)(hp + 8);
            float4 v3 = *(const float4*)(hp + 12);
            a[0]+=al*v0.x; a[1]+=al*v0.y; a[2]+=al*v0.z;  a[3]+=al*v0.w;
            a[4]+=al*v1.x; a[5]+=al*v1.y; a[6]+=al*v1.z;  a[7]+=al*v1.w;
            a[8]+=al*v2.x; a[9]+=al*v2.y; a[10]+=al*v2.z; a[11]+=al*v2.w;
            a[12]+=al*v3.x;a[13]+=al*v3.y;a[14]+=al*v3.z; a[15]+=al*v3.w;
        }
    }
    float w = attn[r];
    float* dst = &lds[nl][L][0];
#pragma unroll
    for (int i = 0; i < 16; ++i) dst[i] = w * fmaxf(a[i], 0.f);   // relu per (n,r)
    __syncthreads();

    // phase 2: sum over relations; dim d=2L lives in phase-1 lane 8*rr + (L>>3),
    // elements 2*(L&7), 2*(L&7)+1
    int o = L >> 3, j = L & 7;
    float s0 = 0.f, s1 = 0.f;
#pragma unroll
    for (int rr = 0; rr < NR; ++rr) {
        s0 += lds[nl][rr * 8 + o][2 * j];
        s1 += lds[nl][rr * 8 + o][2 * j + 1];
    }
    *(float2*)(comb + (size_t)n * 128 + 2 * L) = make_float2(s0, s1);
}

// ---------- link head ----------
__global__ __launch_bounds__(256) void head_kernel(
    const float* __restrict__ hfin, const int* __restrict__ eli,
    const float* __restrict__ pw, const float* __restrict__ pb,
    float* __restrict__ out)
{
    int t = threadIdx.x;
    int l = blockIdx.x * 4 + (t >> 6);        // grid 32768 -> l < 131072 exactly
    int d0 = (t & 63) * 2;
    int a = eli[l], b = eli[NL + l];
    float2 ha = *(const float2*)(hfin + (size_t)a * 128 + d0);
    float2 hb = *(const float2*)(hfin + (size_t)b * 128 + d0);
    float w0 = pw[d0 * 2] + pw[d0 * 2 + 1];
    float w1 = pw[d0 * 2 + 2] + pw[d0 * 2 + 3];
    float v = ha.x * hb.x * w0 + ha.y * hb.y * w1;
    for (int off = 32; off > 0; off >>= 1) v += __shfl_down(v, off);
    if ((t & 63) == 0) out[l] = v + pb[0] + pb[1];
}

extern "C" void kernel_launch(void* const* d_in, const int* in_sizes, int n_in,
                              void* d_out, int out_size, void* d_ws, size_t ws_size,
                              hipStream_t stream)
{
    const float* x     = (const float*)d_in[0];
    const int*   ei    = (const int*)d_in[1];
    const int*   eli   = (const int*)d_in[2];
    const float* w1    = (const float*)d_in[3];
    const float* b1    = (const float*)d_in[4];
    const float* asrc1 = (const float*)d_in[5];
    const float* adst1 = (const float*)d_in[6];
    const float* q1    = (const float*)d_in[7];
    const float* kw1   = (const float*)d_in[8];
    const float* kb1   = (const float*)d_in[9];
    const float* w2    = (const float*)d_in[10];
    const float* b2    = (const float*)d_in[11];
    const float* asrc2 = (const float*)d_in[12];
    const float* adst2 = (const float*)d_in[13];
    const float* q2    = (const float*)d_in[14];
    const float* kw2   = (const float*)d_in[15];
    const float* kb2   = (const float*)d_in[16];
    const float* pw    = (const float*)d_in[17];
    const float* pb    = (const float*)d_in[18];
    float* out = (float*)d_out;

    // ---- workspace layout (float offsets); total ~128.2 MB ----
    float* ws      = (float*)d_ws;
    float* hA      = ws;                         // 12,800,000
    float* hB      = ws + 12800000ull;           // 12,800,000
    float* a_src   = ws + 25600000ull;           // 800,000
    float* a_dst   = ws + 26400000ull;           // 800,000
    int2*  es      = (int2*)(ws + 27200000ull);  // 1,600,000 x int2 (src, alpha)
    int*   rowptr  = (int*)(ws + 30400000ull);   // 800,768 (padded)
    int*   counts  = (int*)(ws + 31200768ull);   // 800,768 (padded; reused as cursor)
    int*   bsums   = (int*)(ws + 32001536ull);   // 1,024
    float* score   = ws + 32002560ull;           // 64
    float* wt      = ws + 32002624ull;           // 16,384
    unsigned short* kw16 = (unsigned short*)(ws + 32019008ull);  // 16,384 ushorts
    // h8 (fp8 custom, 12.8M bytes = 6.4 MB... NN*128 = 12.8 MB) aliases hB:
    // hB's previous content (layer input) is dead once gemm_proj consumed it;
    // combine_csr overwrites hB only after the score path finished (stream-ordered).
    unsigned char* h8 = (unsigned char*)hB;

    // ---- CSR build (edge_index is layer-invariant: build once) ----
    hipMemsetAsync(counts, 0, NPAD * sizeof(int), stream);
    hist_kernel<<<6250, 256, 0, stream>>>(ei, counts);
    scan_k1<<<NB_SCAN, 256, 0, stream>>>(counts, rowptr, bsums);
    scan_k2<<<1, 256, 0, stream>>>(bsums, NB_SCAN);
    scan_k3<<<3126, 256, 0, stream>>>(rowptr, bsums);
    hipMemsetAsync(counts, 0, NPAD * sizeof(int), stream);
    fill_kernel<<<6250, 256, 0, stream>>>(ei, rowptr, counts, (int*)es);

    for (int layer = 0; layer < 2; ++layer) {
        const float* Ain  = layer ? hB : x;
        const float* W    = layer ? w2 : w1;
        const float* bb   = layer ? b2 : b1;
        const float* as_w = layer ? asrc2 : asrc1;
        const float* ad_w = layer ? adst2 : adst1;
        const float* qq   = layer ? q2 : q1;
        const float* kw   = layer ? kw2 : kw1;
        const float* kb   = layer ? kb2 : kb1;

        transpose128<<<64, 256, 0, stream>>>(W, wt);
        gemm_proj<<<782, 256, 0, stream>>>(Ain, wt, bb, hA, NN);
        cast_bf16<<<16, 256, 0, stream>>>(kw, kw16);
        att_kernel<<<6250, 256, 0, stream>>>(hA, as_w, ad_w, a_src, a_dst, h8);
        softmax_csr<<<3125, 256, 0, stream>>>(rowptr, es, a_src, a_dst, score);
        fused_score3<<<dim3(1563, NR), 512, 0, stream>>>(rowptr, es, h8,
                                                         kw16, kb, qq, score);
        combine_csr<<<25000, 256, 0, stream>>>(rowptr, es, hA, score, hB);
        // hB now holds this layer's output embeddings
    }
    head_kernel<<<32768, 256, 0, stream>>>(hB, eli, pw, pb, out);
}